// Round 8
// baseline (223.616 us; speedup 1.0000x reference)
//
#include <hip/hip_runtime.h>
#include <math.h>

typedef __attribute__((ext_vector_type(8)))  short short8;   // 8 x bf16 (4 VGPR) MFMA operand
typedef __attribute__((ext_vector_type(16))) float float16;  // 32x32 MFMA accumulator
typedef __attribute__((ext_vector_type(4), aligned(4))) float float4a; // 4-B-aligned float4

#define DEVI __device__ __forceinline__

DEVI short f2bf(float f) {                      // RNE float -> bf16 bits
    unsigned u = __float_as_uint(f);
    u = (u + 0x7fffu + ((u >> 16) & 1u)) >> 16;
    return (short)u;
}
DEVI unsigned pk2(float a, float b) {
    return (unsigned)(unsigned short)f2bf(a) | ((unsigned)(unsigned short)f2bf(b) << 16);
}
DEVI float16 mfma16(short8 a, short8 b, float16 c) {
    return __builtin_amdgcn_mfma_f32_32x32x16_bf16(a, b, c, 0, 0, 0);
}
// C/D row for reg r, half h: row = (r&3) + 8*(r>>2) + 4*h  [verified]
DEVI int rowof(int r, int h) { return (r & 3) + 8 * (r >> 2) + 4 * h; }
DEVI short8 lds8(const short* p) { return *(const short8*)p; }
DEVI short8 gld8(const short* p) { return *(const short8*)p; }

// ---- ws layout (shorts): MFMA-native [ceil(K/16)][N][16] bf16 ----
#define W1T_OFF  0          // [23][512][16] (K=365 pad 368)
#define W2T_OFF  188416     // [32][256][16]
#define W3T_OFF  319488     // [16][128][16]
#define WC1T_OFF 352256     // [10][64][16]
#define WC2T_OFF 362496     // [4][32][16]

// ---------------- prologue: coalesced weight transpose via LDS tiles ---------
__global__ void prep_v2(const float* __restrict__ W1, const float* __restrict__ W2,
                        const float* __restrict__ W3, const float* __restrict__ Wc1,
                        const float* __restrict__ Wc2, short* __restrict__ ws) {
    __shared__ short T[16 * 72];
    int b = blockIdx.x, t = threadIdx.x;
    const float* src; int K, N; size_t base; int kc, nb;
    if (b < 184)        {            src = W1;  K = 365; N = 512; base = W1T_OFF;  kc = b >> 3;  nb = b & 7; }
    else if (b < 312)   { int l = b - 184; src = W2;  K = 512; N = 256; base = W2T_OFF;  kc = l >> 2;  nb = l & 3; }
    else if (b < 344)   { int l = b - 312; src = W3;  K = 256; N = 128; base = W3T_OFF;  kc = l >> 1;  nb = l & 1; }
    else if (b < 354)   {            src = Wc1; K = 160; N = 64;  base = WC1T_OFF; kc = b - 344; nb = 0; }
    else                {            src = Wc2; K = 64;  N = 32;  base = WC2T_OFF; kc = b - 354; nb = 0; }
    int n = nb * 64 + (t & 63);
    int kr = t >> 6;
    #pragma unroll
    for (int i = 0; i < 4; ++i) {
        int krow = kr + 4 * i;
        int k = kc * 16 + krow;
        float v = (k < K && n < N) ? src[(size_t)k * N + n] : 0.f;
        T[krow * 72 + (t & 63)] = f2bf(v);
    }
    __syncthreads();
    int n2 = t >> 2, ksq = (t & 3) * 4;
    int ng = nb * 64 + n2;
    if (ng < N) {
        unsigned lo = (unsigned)(unsigned short)T[ksq * 72 + n2]
                    | ((unsigned)(unsigned short)T[(ksq + 1) * 72 + n2] << 16);
        unsigned hi = (unsigned)(unsigned short)T[(ksq + 2) * 72 + n2]
                    | ((unsigned)(unsigned short)T[(ksq + 3) * 72 + n2] << 16);
        uint2 d; d.x = lo; d.y = hi;
        *(uint2*)(ws + base + ((size_t)kc * N + ng) * 16 + ksq) = d;
    }
}

// ---------------- fused main: BM=64, 1024 blocks x 512 threads ----------------
// v11 = verified v7 (88.0 us) with: (a) all cross-barrier prefetches removed
// (v10 showed neutral + G4/G5 ones spilled to scratch: 4 MB WRITE_SIZE), and
// (b) G5+final merged: the Wc3 dot is a 5-step shfl_xor tree inside the G5
// waves (lanes hold c2[row][m] already), sigmoid+store from lanes m==0.
// Removes 1 barrier, C2 staging (16 writes + 32 stride-33 reads/thread), and
// the serial 64-thread final phase. Numerics: f32 dot order serial->tree
// (+-ULP; absmax unchanged).
__global__ __launch_bounds__(512, 4)
void fused_v11(const float* __restrict__ x,
               const float* __restrict__ b1f, const float* __restrict__ b2f,
               const float* __restrict__ b3f, const float* __restrict__ Wsf,
               const float* __restrict__ bsf, const float* __restrict__ bc1f,
               const float* __restrict__ bc2f, const float* __restrict__ Wc3f,
               const float* __restrict__ bc3f,
               const short* __restrict__ wsw, float* __restrict__ out)
{
    __shared__ __align__(16) char smem[70656];
    short* XT    = (short*)smem;               // [64][376] bf16 x-tile (48128 B)
    short* SB    = (short*)(smem + 48128);     // [64][136] staging (17408 B)
    short* FEATL = (short*)(smem + 65536);     // [64][40]  (5120 B, DEDICATED)
    short* C1    = (short*)smem;               // [64][72]  (aliases XT, x dead)

    const short* W1t  = wsw + W1T_OFF;
    const short* W2t  = wsw + W2T_OFF;
    const short* W3t  = wsw + W3T_OFF;
    const short* Wc1t = wsw + WC1T_OFF;
    const short* Wc2t = wsw + WC2T_OFF;

    const int tid  = (int)threadIdx.x;
    const int lane = tid & 63;
    const int wv   = tid >> 6;       // 0..7 = col-group owner (dup-free B)
    const int m    = lane & 31;
    const int h    = lane >> 5;
    const int rowBase = (int)blockIdx.x * 64;

    // bias prefetch (overlaps x-phase)
    float bb1a = b1f[32 * wv + m];
    float bb1b = b1f[256 + 32 * wv + m];
    float bb2  = b2f[32 * wv + m];
    float bb3  = b3f[32 * (wv & 3) + m];

    // ---- fill XT + fused row moments (coalesced float4 loads) ----
    // wave wv owns rows 8wv..8wv+8; lane: rw=row-in-wave, q=float4 slot
    const int rw = lane >> 3, q = lane & 7;
    const int xr = 8 * wv + rw;                 // row 0..63
    const float* xrow = x + (size_t)(rowBase + xr) * 365;
    float s1 = 0.f, s2 = 0.f, s3 = 0.f, s4 = 0.f, mn = 1e30f, mx = -1e30f;
    #pragma unroll
    for (int i = 0; i < 11; ++i) {              // cols [32i+4q, +4), all < 352 valid
        float4a v = *(const float4a*)(xrow + 32 * i + 4 * q);
        #pragma unroll
        for (int j = 0; j < 4; ++j) {
            float f = v[j], f2 = f * f;
            s1 += f; s2 += f2; s3 += f2 * f; s4 += f2 * f2;
            mn = fminf(mn, f); mx = fmaxf(mx, f);
        }
        uint2 d; d.x = pk2(v[0], v[1]); d.y = pk2(v[2], v[3]);
        *(uint2*)(XT + xr * 376 + 32 * i + 4 * q) = d;
    }
    // tail: cols 352..367 (365..367 pad zero; cols >=368 never read by G1)
    if (q < 3) {
        float4a v = *(const float4a*)(xrow + 352 + 4 * q);
        #pragma unroll
        for (int j = 0; j < 4; ++j) {
            float f = v[j], f2 = f * f;
            s1 += f; s2 += f2; s3 += f2 * f; s4 += f2 * f2;
            mn = fminf(mn, f); mx = fmaxf(mx, f);
        }
        uint2 d; d.x = pk2(v[0], v[1]); d.y = pk2(v[2], v[3]);
        *(uint2*)(XT + xr * 376 + 352 + 4 * q) = d;
    } else if (q == 3) {
        float f = xrow[364];
        float f2 = f * f;
        s1 += f; s2 += f2; s3 += f2 * f; s4 += f2 * f2;
        mn = fminf(mn, f); mx = fmaxf(mx, f);
        uint2 d; d.x = pk2(f, 0.f); d.y = 0u;
        *(uint2*)(XT + xr * 376 + 364) = d;
    }
    // reduce across the 8 lanes sharing a row (consecutive lanes)
    #pragma unroll
    for (int off = 1; off <= 4; off <<= 1) {
        s1 += __shfl_xor(s1, off); s2 += __shfl_xor(s2, off);
        s3 += __shfl_xor(s3, off); s4 += __shfl_xor(s4, off);
        mn = fminf(mn, __shfl_xor(mn, off)); mx = fmaxf(mx, __shfl_xor(mx, off));
    }
    {
        float mean  = s1 * (1.0f / 365.0f);
        float var1  = (s2 - 365.0f * mean * mean) * (1.0f / 364.0f);
        float sigma = sqrtf(var1);
        float m3 = (s3 - 3.0f * mean * s2) * (1.0f / 365.0f) + 2.0f * mean * mean * mean;
        float mm = mean * mean;
        float m4 = (s4 - 4.0f * mean * s3 + 6.0f * mm * s2) * (1.0f / 365.0f) - 3.0f * mm * mm;
        float sg2 = sigma * sigma;
        float skew = m3 / (sigma * sg2 + 1e-8f);
        float kurt = m4 / (sg2 * sg2 + 1e-8f);
        float st[6] = { mean, sigma, mn, mx, skew, kurt };
        float f[4];
        #pragma unroll
        for (int c0 = 0; c0 < 4; ++c0) {
            int c = 4 * q + c0;
            float acc = bsf[c];
            #pragma unroll
            for (int jj = 0; jj < 6; ++jj) acc += st[jj] * Wsf[jj * 32 + c];
            f[c0] = acc;
        }
        // store feat NOW — dedicated region, frees all stats registers pre-G1
        *(unsigned*)(FEATL + xr * 40 + 4 * q)     = pk2(f[0], f[1]);
        *(unsigned*)(FEATL + xr * 40 + 4 * q + 2) = pk2(f[2], f[3]);
    }
    __syncthreads();                            // XT (+FEATL) ready

    // ---- G1 (2 passes of 256 cols, dup-free) interleaved with G2 slabs ----
    float16 ha0, ha1;                           // h2 rows 0-31 / 32-63, cols 32wv..+32
    #pragma unroll
    for (int i = 0; i < 16; ++i) { ha0[i] = 0.f; ha1[i] = 0.f; }

    const short* Ap0  = XT + m * 376 + h * 8;
    const short* Ap1  = XT + (32 + m) * 376 + h * 8;
    const short* A2p0 = SB + m * 136 + h * 8;
    const short* A2p1 = SB + (32 + m) * 136 + h * 8;
    const int stcol = 32 * (wv & 3) + m;        // staging col for writer waves

    #pragma unroll
    for (int p = 0; p < 2; ++p) {
        float16 ga0, ga1;
        #pragma unroll
        for (int i = 0; i < 16; ++i) { ga0[i] = 0.f; ga1[i] = 0.f; }
        const short* B1 = W1t + (256 * p + 32 * wv + m) * 16 + h * 8;
        #pragma unroll
        for (int kc = 0; kc < 23; ++kc) {
            short8 b  = gld8(B1 + kc * 8192);
            short8 a0 = lds8(Ap0 + kc * 16);
            short8 a1 = lds8(Ap1 + kc * 16);
            ga0 = mfma16(a0, b, ga0);
            ga1 = mfma16(a1, b, ga1);
        }
        float bb = p ? bb1b : bb1a;
        #pragma unroll
        for (int s = 0; s < 2; ++s) {
            int sl = 2 * p + s;
            __syncthreads();                    // prior SB consumers done
            if ((wv >> 2) == s) {               // waves [4s,4s+4) stage their cols
                #pragma unroll
                for (int r = 0; r < 16; ++r) {
                    SB[rowof(r, h) * 136 + stcol]        = f2bf(fmaxf(ga0[r] + bb, 0.f));
                    SB[(32 + rowof(r, h)) * 136 + stcol] = f2bf(fmaxf(ga1[r] + bb, 0.f));
                }
            }
            __syncthreads();                    // slab staged
            const short* B2 = W2t + sl * 8 * 4096 + (32 * wv + m) * 16 + h * 8;
            #pragma unroll
            for (int i = 0; i < 8; ++i) {
                short8 b  = gld8(B2 + i * 4096);
                short8 a0 = lds8(A2p0 + i * 16);
                short8 a1 = lds8(A2p1 + i * 16);
                ha0 = mfma16(a0, b, ha0);
                ha1 = mfma16(a1, b, ha1);
            }
        }
    }

    // ---- G3: seq = relu(h2 @ W3 + b3), K=256 via 2 staged slabs ----
    float16 g3;
    #pragma unroll
    for (int i = 0; i < 16; ++i) g3[i] = 0.f;
    const short* A3p = SB + ((wv >> 2) * 32 + m) * 136 + h * 8;
    #pragma unroll
    for (int t = 0; t < 2; ++t) {
        __syncthreads();
        if ((wv >> 2) == t) {                   // stage h2 cols [128t,128t+128)
            #pragma unroll
            for (int r = 0; r < 16; ++r) {
                SB[rowof(r, h) * 136 + stcol]        = f2bf(fmaxf(ha0[r] + bb2, 0.f));
                SB[(32 + rowof(r, h)) * 136 + stcol] = f2bf(fmaxf(ha1[r] + bb2, 0.f));
            }
        }
        __syncthreads();
        const short* B3 = W3t + t * 8 * 2048 + (32 * (wv & 3) + m) * 16 + h * 8;
        #pragma unroll
        for (int i = 0; i < 8; ++i) {
            short8 b = gld8(B3 + i * 2048);
            short8 a = lds8(A3p + i * 16);
            g3 = mfma16(a, b, g3);
        }
    }

    // ---- stage seq (full [64][128]) ----
    __syncthreads();
    {
        int rb = (wv >> 2) * 32;
        #pragma unroll
        for (int r = 0; r < 16; ++r)
            SB[(rb + rowof(r, h)) * 136 + stcol] = f2bf(fmaxf(g3[r] + bb3, 0.f));
    }
    __syncthreads();

    // ---- G4: c1 = relu([seq|feat] @ Wc1 + bc1), K=160, waves 0..3 ----
    if (wv < 4) {
        int m4 = wv & 1, c4 = wv >> 1;
        const short* B4 = Wc1t + (32 * c4 + m) * 16 + h * 8;
        const short* A4 = SB + (m4 * 32 + m) * 136 + h * 8;
        float16 g4;
        #pragma unroll
        for (int i = 0; i < 16; ++i) g4[i] = 0.f;
        #pragma unroll
        for (int i = 0; i < 8; ++i) {
            short8 b = gld8(B4 + i * 1024);
            short8 a = lds8(A4 + i * 16);
            g4 = mfma16(a, b, g4);
        }
        const short* AF = FEATL + (m4 * 32 + m) * 40 + h * 8;
        #pragma unroll
        for (int i = 0; i < 2; ++i) {
            short8 b = gld8(B4 + (8 + i) * 1024);
            short8 a = lds8(AF + i * 16);
            g4 = mfma16(a, b, g4);
        }
        float bb = bc1f[32 * c4 + m];
        #pragma unroll
        for (int r = 0; r < 16; ++r)
            C1[(m4 * 32 + rowof(r, h)) * 72 + 32 * c4 + m] = f2bf(fmaxf(g4[r] + bb, 0.f));
    }
    __syncthreads();

    // ---- G5+final (merged): c2 = relu(c1 @ Wc2 + bc2); out = sigmoid(c2.Wc3+bc3)
    // Lane (m,h) of wave wv holds c2[32wv + rowof(r,h)][m]; the Wc3 dot is a
    // 5-step shfl_xor tree over m within each 32-lane half; lanes m==0 store.
    if (wv < 2) {
        const short* B5 = Wc2t + m * 16 + h * 8;
        const short* A5 = C1 + (wv * 32 + m) * 72 + h * 8;
        float16 g5;
        #pragma unroll
        for (int i = 0; i < 16; ++i) g5[i] = 0.f;
        #pragma unroll
        for (int i = 0; i < 4; ++i) {
            short8 b = gld8(B5 + i * 512);
            short8 a = lds8(A5 + i * 16);
            g5 = mfma16(a, b, g5);
        }
        float bb  = bc2f[m];
        float wc  = Wc3f[m];
        float bz  = bc3f[0];
        #pragma unroll
        for (int r = 0; r < 16; ++r) {
            float c2v = fmaxf(g5[r] + bb, 0.f);
            float t = c2v * wc;
            t += __shfl_xor(t, 1);
            t += __shfl_xor(t, 2);
            t += __shfl_xor(t, 4);
            t += __shfl_xor(t, 8);
            t += __shfl_xor(t, 16);
            if (m == 0) {
                float z = t + bz;
                out[rowBase + 32 * wv + rowof(r, h)] = 1.0f / (1.0f + expf(-z));
            }
        }
    }
}

extern "C" void kernel_launch(void* const* d_in, const int* in_sizes, int n_in,
                              void* d_out, int out_size, void* d_ws, size_t ws_size,
                              hipStream_t stream)
{
    (void)in_sizes; (void)n_in; (void)out_size; (void)ws_size;
    const float* x   = (const float*)d_in[0];
    const float* W1  = (const float*)d_in[1];
    const float* b1  = (const float*)d_in[2];
    const float* W2  = (const float*)d_in[3];
    const float* b2  = (const float*)d_in[4];
    const float* W3  = (const float*)d_in[5];
    const float* b3  = (const float*)d_in[6];
    const float* Ws  = (const float*)d_in[7];
    const float* bs  = (const float*)d_in[8];
    const float* Wc1 = (const float*)d_in[9];
    const float* bc1 = (const float*)d_in[10];
    const float* Wc2 = (const float*)d_in[11];
    const float* bc2 = (const float*)d_in[12];
    const float* Wc3 = (const float*)d_in[13];
    const float* bc3 = (const float*)d_in[14];
    short* ws = (short*)d_ws;

    prep_v2<<<358, 256, 0, stream>>>(W1, W2, W3, Wc1, Wc2, ws);
    fused_v11<<<1024, 512, 0, stream>>>(x, b1, b2, b3, Ws, bs, bc1, bc2, Wc3, bc3,
                                        ws, (float*)d_out);
}

// Round 9
// 214.818 us; speedup vs baseline: 1.0410x; 1.0410x over previous
//
#include <hip/hip_runtime.h>
#include <math.h>

typedef __attribute__((ext_vector_type(8)))  short short8;   // 8 x bf16 (4 VGPR) MFMA operand
typedef __attribute__((ext_vector_type(16))) float float16;  // 32x32 MFMA accumulator
typedef __attribute__((ext_vector_type(4), aligned(4))) float float4a; // 4-B-aligned float4

#define DEVI __device__ __forceinline__

DEVI short f2bf(float f) {                      // RNE float -> bf16 bits
    unsigned u = __float_as_uint(f);
    u = (u + 0x7fffu + ((u >> 16) & 1u)) >> 16;
    return (short)u;
}
DEVI unsigned pk2(float a, float b) {
    return (unsigned)(unsigned short)f2bf(a) | ((unsigned)(unsigned short)f2bf(b) << 16);
}
DEVI float16 mfma16(short8 a, short8 b, float16 c) {
    return __builtin_amdgcn_mfma_f32_32x32x16_bf16(a, b, c, 0, 0, 0);
}
// C/D row for reg r, half h: row = (r&3) + 8*(r>>2) + 4*h  [verified]
DEVI int rowof(int r, int h) { return (r & 3) + 8 * (r >> 2) + 4 * h; }
DEVI short8 lds8(const short* p) { return *(const short8*)p; }
DEVI short8 gld8(const short* p) { return *(const short8*)p; }

// ---- ws layout (shorts): MFMA-native [ceil(K/16)][N][16] bf16 ----
#define W1T_OFF  0          // [23][512][16] (K=365 pad 368)
#define W2T_OFF  188416     // [32][256][16]
#define W3T_OFF  319488     // [16][128][16]
#define WC1T_OFF 352256     // [10][64][16]
#define WC2T_OFF 362496     // [4][32][16]

// ---------------- prologue: coalesced weight transpose via LDS tiles ---------
__global__ void prep_v2(const float* __restrict__ W1, const float* __restrict__ W2,
                        const float* __restrict__ W3, const float* __restrict__ Wc1,
                        const float* __restrict__ Wc2, short* __restrict__ ws) {
    __shared__ short T[16 * 72];
    int b = blockIdx.x, t = threadIdx.x;
    const float* src; int K, N; size_t base; int kc, nb;
    if (b < 184)        {            src = W1;  K = 365; N = 512; base = W1T_OFF;  kc = b >> 3;  nb = b & 7; }
    else if (b < 312)   { int l = b - 184; src = W2;  K = 512; N = 256; base = W2T_OFF;  kc = l >> 2;  nb = l & 3; }
    else if (b < 344)   { int l = b - 312; src = W3;  K = 256; N = 128; base = W3T_OFF;  kc = l >> 1;  nb = l & 1; }
    else if (b < 354)   {            src = Wc1; K = 160; N = 64;  base = WC1T_OFF; kc = b - 344; nb = 0; }
    else                {            src = Wc2; K = 64;  N = 32;  base = WC2T_OFF; kc = b - 354; nb = 0; }
    int n = nb * 64 + (t & 63);
    int kr = t >> 6;
    #pragma unroll
    for (int i = 0; i < 4; ++i) {
        int krow = kr + 4 * i;
        int k = kc * 16 + krow;
        float v = (k < K && n < N) ? src[(size_t)k * N + n] : 0.f;
        T[krow * 72 + (t & 63)] = f2bf(v);
    }
    __syncthreads();
    int n2 = t >> 2, ksq = (t & 3) * 4;
    int ng = nb * 64 + n2;
    if (ng < N) {
        unsigned lo = (unsigned)(unsigned short)T[ksq * 72 + n2]
                    | ((unsigned)(unsigned short)T[(ksq + 1) * 72 + n2] << 16);
        unsigned hi = (unsigned)(unsigned short)T[(ksq + 2) * 72 + n2]
                    | ((unsigned)(unsigned short)T[(ksq + 3) * 72 + n2] << 16);
        uint2 d; d.x = lo; d.y = hi;
        *(uint2*)(ws + base + ((size_t)kc * N + ng) * 16 + ksq) = d;
    }
}

// ---------------- fused main: BM=64, 1024 blocks x 512 threads ----------------
// v12 == v7 VERBATIM (verified best: 88.0 us fused, reproduced 3x).
// Probed and rejected around this point: barrier-lean restructure (+17us, v9),
// cross-barrier B-prefetch (neutral, v10), G5+final shfl-merge (+7us, v11),
// x-phase in prep kernel (net worse, v5). Occupancy is register-capped at
// 2 blocks/CU (64 VGPR + 64 AGPR accumulators); LDS 70,656 B co-caps at 2.
__global__ __launch_bounds__(512, 4)
void fused_v7(const float* __restrict__ x,
              const float* __restrict__ b1f, const float* __restrict__ b2f,
              const float* __restrict__ b3f, const float* __restrict__ Wsf,
              const float* __restrict__ bsf, const float* __restrict__ bc1f,
              const float* __restrict__ bc2f, const float* __restrict__ Wc3f,
              const float* __restrict__ bc3f,
              const short* __restrict__ wsw, float* __restrict__ out)
{
    __shared__ __align__(16) char smem[70656];
    short* XT    = (short*)smem;               // [64][376] bf16 x-tile (48128 B)
    short* SB    = (short*)(smem + 48128);     // [64][136] staging (17408 B)
    short* FEATL = (short*)(smem + 65536);     // [64][40]  (5120 B, DEDICATED)
    short* C1    = (short*)smem;               // [64][72]  (aliases XT, x dead)
    float* C2    = (float*)(smem + 20480);     // [64][33]  f32 (aliases XT)

    const short* W1t  = wsw + W1T_OFF;
    const short* W2t  = wsw + W2T_OFF;
    const short* W3t  = wsw + W3T_OFF;
    const short* Wc1t = wsw + WC1T_OFF;
    const short* Wc2t = wsw + WC2T_OFF;

    const int tid  = (int)threadIdx.x;
    const int lane = tid & 63;
    const int wv   = tid >> 6;       // 0..7 = col-group owner (dup-free B)
    const int m    = lane & 31;
    const int h    = lane >> 5;
    const int rowBase = (int)blockIdx.x * 64;

    // bias prefetch (overlaps x-phase)
    float bb1a = b1f[32 * wv + m];
    float bb1b = b1f[256 + 32 * wv + m];
    float bb2  = b2f[32 * wv + m];
    float bb3  = b3f[32 * (wv & 3) + m];

    // ---- fill XT + fused row moments (coalesced float4 loads) ----
    // wave wv owns rows 8wv..8wv+8; lane: rw=row-in-wave, q=float4 slot
    const int rw = lane >> 3, q = lane & 7;
    const int xr = 8 * wv + rw;                 // row 0..63
    const float* xrow = x + (size_t)(rowBase + xr) * 365;
    float s1 = 0.f, s2 = 0.f, s3 = 0.f, s4 = 0.f, mn = 1e30f, mx = -1e30f;
    #pragma unroll
    for (int i = 0; i < 11; ++i) {              // cols [32i+4q, +4), all < 352 valid
        float4a v = *(const float4a*)(xrow + 32 * i + 4 * q);
        #pragma unroll
        for (int j = 0; j < 4; ++j) {
            float f = v[j], f2 = f * f;
            s1 += f; s2 += f2; s3 += f2 * f; s4 += f2 * f2;
            mn = fminf(mn, f); mx = fmaxf(mx, f);
        }
        uint2 d; d.x = pk2(v[0], v[1]); d.y = pk2(v[2], v[3]);
        *(uint2*)(XT + xr * 376 + 32 * i + 4 * q) = d;
    }
    // tail: cols 352..367 (365..367 pad zero; cols >=368 never read by G1)
    if (q < 3) {
        float4a v = *(const float4a*)(xrow + 352 + 4 * q);
        #pragma unroll
        for (int j = 0; j < 4; ++j) {
            float f = v[j], f2 = f * f;
            s1 += f; s2 += f2; s3 += f2 * f; s4 += f2 * f2;
            mn = fminf(mn, f); mx = fmaxf(mx, f);
        }
        uint2 d; d.x = pk2(v[0], v[1]); d.y = pk2(v[2], v[3]);
        *(uint2*)(XT + xr * 376 + 352 + 4 * q) = d;
    } else if (q == 3) {
        float f = xrow[364];
        float f2 = f * f;
        s1 += f; s2 += f2; s3 += f2 * f; s4 += f2 * f2;
        mn = fminf(mn, f); mx = fmaxf(mx, f);
        uint2 d; d.x = pk2(f, 0.f); d.y = 0u;
        *(uint2*)(XT + xr * 376 + 364) = d;
    }
    // reduce across the 8 lanes sharing a row (consecutive lanes)
    #pragma unroll
    for (int off = 1; off <= 4; off <<= 1) {
        s1 += __shfl_xor(s1, off); s2 += __shfl_xor(s2, off);
        s3 += __shfl_xor(s3, off); s4 += __shfl_xor(s4, off);
        mn = fminf(mn, __shfl_xor(mn, off)); mx = fmaxf(mx, __shfl_xor(mx, off));
    }
    {
        float mean  = s1 * (1.0f / 365.0f);
        float var1  = (s2 - 365.0f * mean * mean) * (1.0f / 364.0f);
        float sigma = sqrtf(var1);
        float m3 = (s3 - 3.0f * mean * s2) * (1.0f / 365.0f) + 2.0f * mean * mean * mean;
        float mm = mean * mean;
        float m4 = (s4 - 4.0f * mean * s3 + 6.0f * mm * s2) * (1.0f / 365.0f) - 3.0f * mm * mm;
        float sg2 = sigma * sigma;
        float skew = m3 / (sigma * sg2 + 1e-8f);
        float kurt = m4 / (sg2 * sg2 + 1e-8f);
        float st[6] = { mean, sigma, mn, mx, skew, kurt };
        float f[4];
        #pragma unroll
        for (int c0 = 0; c0 < 4; ++c0) {
            int c = 4 * q + c0;
            float acc = bsf[c];
            #pragma unroll
            for (int jj = 0; jj < 6; ++jj) acc += st[jj] * Wsf[jj * 32 + c];
            f[c0] = acc;
        }
        // store feat NOW — dedicated region, frees all stats registers pre-G1
        *(unsigned*)(FEATL + xr * 40 + 4 * q)     = pk2(f[0], f[1]);
        *(unsigned*)(FEATL + xr * 40 + 4 * q + 2) = pk2(f[2], f[3]);
    }
    __syncthreads();                            // XT (+FEATL) ready

    // ---- G1 (2 passes of 256 cols, dup-free) interleaved with G2 slabs ----
    float16 ha0, ha1;                           // h2 rows 0-31 / 32-63, cols 32wv..+32
    #pragma unroll
    for (int i = 0; i < 16; ++i) { ha0[i] = 0.f; ha1[i] = 0.f; }

    const short* Ap0  = XT + m * 376 + h * 8;
    const short* Ap1  = XT + (32 + m) * 376 + h * 8;
    const short* A2p0 = SB + m * 136 + h * 8;
    const short* A2p1 = SB + (32 + m) * 136 + h * 8;
    const int stcol = 32 * (wv & 3) + m;        // staging col for writer waves

    #pragma unroll
    for (int p = 0; p < 2; ++p) {
        float16 ga0, ga1;
        #pragma unroll
        for (int i = 0; i < 16; ++i) { ga0[i] = 0.f; ga1[i] = 0.f; }
        const short* B1 = W1t + (256 * p + 32 * wv + m) * 16 + h * 8;
        #pragma unroll
        for (int kc = 0; kc < 23; ++kc) {
            short8 b  = gld8(B1 + kc * 8192);
            short8 a0 = lds8(Ap0 + kc * 16);
            short8 a1 = lds8(Ap1 + kc * 16);
            ga0 = mfma16(a0, b, ga0);
            ga1 = mfma16(a1, b, ga1);
        }
        float bb = p ? bb1b : bb1a;
        #pragma unroll
        for (int s = 0; s < 2; ++s) {
            int sl = 2 * p + s;
            __syncthreads();                    // prior SB consumers done
            if ((wv >> 2) == s) {               // waves [4s,4s+4) stage their cols
                #pragma unroll
                for (int r = 0; r < 16; ++r) {
                    SB[rowof(r, h) * 136 + stcol]        = f2bf(fmaxf(ga0[r] + bb, 0.f));
                    SB[(32 + rowof(r, h)) * 136 + stcol] = f2bf(fmaxf(ga1[r] + bb, 0.f));
                }
            }
            __syncthreads();                    // slab staged
            const short* B2 = W2t + sl * 8 * 4096 + (32 * wv + m) * 16 + h * 8;
            #pragma unroll
            for (int i = 0; i < 8; ++i) {
                short8 b  = gld8(B2 + i * 4096);
                short8 a0 = lds8(A2p0 + i * 16);
                short8 a1 = lds8(A2p1 + i * 16);
                ha0 = mfma16(a0, b, ha0);
                ha1 = mfma16(a1, b, ha1);
            }
        }
    }

    // ---- G3: seq = relu(h2 @ W3 + b3), K=256 via 2 staged slabs ----
    float16 g3;
    #pragma unroll
    for (int i = 0; i < 16; ++i) g3[i] = 0.f;
    const short* A3p = SB + ((wv >> 2) * 32 + m) * 136 + h * 8;
    #pragma unroll
    for (int t = 0; t < 2; ++t) {
        __syncthreads();
        if ((wv >> 2) == t) {                   // stage h2 cols [128t,128t+128)
            #pragma unroll
            for (int r = 0; r < 16; ++r) {
                SB[rowof(r, h) * 136 + stcol]        = f2bf(fmaxf(ha0[r] + bb2, 0.f));
                SB[(32 + rowof(r, h)) * 136 + stcol] = f2bf(fmaxf(ha1[r] + bb2, 0.f));
            }
        }
        __syncthreads();
        const short* B3 = W3t + t * 8 * 2048 + (32 * (wv & 3) + m) * 16 + h * 8;
        #pragma unroll
        for (int i = 0; i < 8; ++i) {
            short8 b = gld8(B3 + i * 2048);
            short8 a = lds8(A3p + i * 16);
            g3 = mfma16(a, b, g3);
        }
    }

    // ---- stage seq (full [64][128]) ----
    __syncthreads();
    {
        int rb = (wv >> 2) * 32;
        #pragma unroll
        for (int r = 0; r < 16; ++r)
            SB[(rb + rowof(r, h)) * 136 + stcol] = f2bf(fmaxf(g3[r] + bb3, 0.f));
    }
    __syncthreads();

    // ---- G4: c1 = relu([seq|feat] @ Wc1 + bc1), K=160, waves 0..3 ----
    if (wv < 4) {
        int m4 = wv & 1, c4 = wv >> 1;
        const short* B4 = Wc1t + (32 * c4 + m) * 16 + h * 8;
        const short* A4 = SB + (m4 * 32 + m) * 136 + h * 8;
        float16 g4;
        #pragma unroll
        for (int i = 0; i < 16; ++i) g4[i] = 0.f;
        #pragma unroll
        for (int i = 0; i < 8; ++i) {
            short8 b = gld8(B4 + i * 1024);
            short8 a = lds8(A4 + i * 16);
            g4 = mfma16(a, b, g4);
        }
        const short* AF = FEATL + (m4 * 32 + m) * 40 + h * 8;
        #pragma unroll
        for (int i = 0; i < 2; ++i) {
            short8 b = gld8(B4 + (8 + i) * 1024);
            short8 a = lds8(AF + i * 16);
            g4 = mfma16(a, b, g4);
        }
        float bb = bc1f[32 * c4 + m];
        #pragma unroll
        for (int r = 0; r < 16; ++r)
            C1[(m4 * 32 + rowof(r, h)) * 72 + 32 * c4 + m] = f2bf(fmaxf(g4[r] + bb, 0.f));
    }
    __syncthreads();

    // ---- G5: c2 = relu(c1 @ Wc2 + bc2) -> C2 f32, waves 0..1 ----
    if (wv < 2) {
        const short* B5 = Wc2t + m * 16 + h * 8;
        const short* A5 = C1 + (wv * 32 + m) * 72 + h * 8;
        float16 g5;
        #pragma unroll
        for (int i = 0; i < 16; ++i) g5[i] = 0.f;
        #pragma unroll
        for (int i = 0; i < 4; ++i) {
            short8 b = gld8(B5 + i * 512);
            short8 a = lds8(A5 + i * 16);
            g5 = mfma16(a, b, g5);
        }
        float bb = bc2f[m];
        #pragma unroll
        for (int r = 0; r < 16; ++r)
            C2[(wv * 32 + rowof(r, h)) * 33 + m] = fmaxf(g5[r] + bb, 0.f);
    }
    __syncthreads();

    // ---- final: out = sigmoid(c2 . Wc3 + bc3) ----
    if (tid < 64) {
        float z = bc3f[0];
        #pragma unroll
        for (int i = 0; i < 32; ++i) z += C2[tid * 33 + i] * Wc3f[i];
        out[rowBase + tid] = 1.0f / (1.0f + expf(-z));
    }
}

extern "C" void kernel_launch(void* const* d_in, const int* in_sizes, int n_in,
                              void* d_out, int out_size, void* d_ws, size_t ws_size,
                              hipStream_t stream)
{
    (void)in_sizes; (void)n_in; (void)out_size; (void)ws_size;
    const float* x   = (const float*)d_in[0];
    const float* W1  = (const float*)d_in[1];
    const float* b1  = (const float*)d_in[2];
    const float* W2  = (const float*)d_in[3];
    const float* b2  = (const float*)d_in[4];
    const float* W3  = (const float*)d_in[5];
    const float* b3  = (const float*)d_in[6];
    const float* Ws  = (const float*)d_in[7];
    const float* bs  = (const float*)d_in[8];
    const float* Wc1 = (const float*)d_in[9];
    const float* bc1 = (const float*)d_in[10];
    const float* Wc2 = (const float*)d_in[11];
    const float* bc2 = (const float*)d_in[12];
    const float* Wc3 = (const float*)d_in[13];
    const float* bc3 = (const float*)d_in[14];
    short* ws = (short*)d_ws;

    prep_v2<<<358, 256, 0, stream>>>(W1, W2, W3, Wc1, Wc2, ws);
    fused_v7<<<1024, 512, 0, stream>>>(x, b1, b2, b3, Ws, bs, bc1, bc2, Wc3, bc3,
                                       ws, (float*)d_out);
}